// Round 1
// baseline (3099.034 us; speedup 1.0000x reference)
//
#include <hip/hip_runtime.h>

// B=8, C=128, T=128, F=512, K=64
static constexpr int Bn = 8, Cc = 128, Tt = 128, Ff = 512, Kk = 64;

__device__ __forceinline__ float silu_f(float x) {
  return x / (1.0f + __expf(-x));
}

// Y[o0..o0+3][f0..f0+3] partial: acc += W[o][c] * X[c][f], c over 128.
// X is LDS [128][64] row-major (row stride 64 floats, 16B-aligned).
// W is global row-major [*][128].
__device__ __forceinline__ void mm_core128(const float* __restrict__ W,
                                           const float* __restrict__ X,
                                           int o0, int f0, float (&acc)[4][4]) {
#pragma unroll 2
  for (int c = 0; c < 128; c += 4) {
    float4 xv0 = *(const float4*)(X + (c + 0) * 64 + f0);
    float4 xv1 = *(const float4*)(X + (c + 1) * 64 + f0);
    float4 xv2 = *(const float4*)(X + (c + 2) * 64 + f0);
    float4 xv3 = *(const float4*)(X + (c + 3) * 64 + f0);
#pragma unroll
    for (int j = 0; j < 4; ++j) {
      float4 wv = *(const float4*)(W + (size_t)(o0 + j) * 128 + c);
      acc[j][0] += wv.x * xv0.x + wv.y * xv1.x + wv.z * xv2.x + wv.w * xv3.x;
      acc[j][1] += wv.x * xv0.y + wv.y * xv1.y + wv.z * xv2.y + wv.w * xv3.y;
      acc[j][2] += wv.x * xv0.z + wv.y * xv1.z + wv.z * xv2.z + wv.w * xv3.z;
      acc[j][3] += wv.x * xv0.w + wv.y * xv1.w + wv.z * xv2.w + wv.w * xv3.w;
    }
  }
}

// Per-frame: latent_h = silu(lp_w @ rmsnorm(latent)*gamma + lp_b); k,v = proj(latent_h)
__global__ __launch_bounds__(512)
void kv_kernel(const float* __restrict__ latent,
               const float* __restrict__ lp_gamma,
               const float* __restrict__ lp_w, const float* __restrict__ lp_b,
               const float* __restrict__ k_w, const float* __restrict__ k_b,
               const float* __restrict__ v_w, const float* __restrict__ v_b,
               float* __restrict__ kbuf, float* __restrict__ vbuf) {
  __shared__ __align__(16) float sx[Cc * Kk];
  __shared__ __align__(16) float sh[Cc * Kk];
  __shared__ float sr[Kk];
  const int tid = threadIdx.x;
  const int fr = blockIdx.x;          // b*T + t
  const int b = fr >> 7, t = fr & 127;
  const size_t base = ((size_t)b * Cc * Tt + t) * Kk;  // latent[b,0,t,0]

#pragma unroll
  for (int i = 0; i < 16; ++i) {
    int idx = i * 512 + tid;
    sx[idx] = latent[base + (size_t)(idx >> 6) * Tt * Kk + (idx & 63)];
  }
  __syncthreads();
  if (tid < Kk) {
    float s = 0.f;
    for (int c = 0; c < Cc; ++c) { float v = sx[c * 64 + tid]; s += v * v; }
    sr[tid] = rsqrtf(s * (1.0f / Cc) + 1e-6f);
  }
  __syncthreads();
#pragma unroll
  for (int i = 0; i < 16; ++i) {
    int idx = i * 512 + tid;
    sx[idx] *= sr[idx & 63] * lp_gamma[idx >> 6];
  }
  __syncthreads();

  const int f0 = (tid & 15) * 4;
  const int o0 = (tid >> 4) * 4;
  {
    float acc[4][4] = {};
    mm_core128(lp_w, sx, o0, f0, acc);
#pragma unroll
    for (int j = 0; j < 4; ++j) {
      float bb = lp_b[o0 + j];
#pragma unroll
      for (int i = 0; i < 4; ++i) sh[(o0 + j) * 64 + f0 + i] = silu_f(acc[j][i] + bb);
    }
  }
  __syncthreads();
  {
    float acc[4][4] = {};
    mm_core128(k_w, sh, o0, f0, acc);
    float* kb = kbuf + (size_t)fr * (Cc * Kk);
#pragma unroll
    for (int j = 0; j < 4; ++j) {
      float bb = k_b[o0 + j];
#pragma unroll
      for (int i = 0; i < 4; ++i) kb[(o0 + j) * 64 + f0 + i] = acc[j][i] + bb;
    }
  }
  {
    float acc[4][4] = {};
    mm_core128(v_w, sh, o0, f0, acc);
    float* vb = vbuf + (size_t)fr * (Cc * Kk);
#pragma unroll
    for (int j = 0; j < 4; ++j) {
      float bb = v_b[o0 + j];
#pragma unroll
      for (int i = 0; i < 4; ++i) vb[(o0 + j) * 64 + f0 + i] = acc[j][i] + bb;
    }
  }
}

// Per (frame, f-tile of 64): full side path + attention + ffn, all in LDS.
__global__ __launch_bounds__(512)
void main_kernel(const float* __restrict__ side, const float* __restrict__ basis,
                 const float* __restrict__ qn_gamma,
                 const float* __restrict__ qin_w, const float* __restrict__ qin_b,
                 const float* __restrict__ qout_w, const float* __restrict__ qout_b,
                 const float* __restrict__ q_w, const float* __restrict__ q_b,
                 const float* __restrict__ o_w, const float* __restrict__ o_b,
                 const float* __restrict__ ffn_gamma,
                 const float* __restrict__ fin_w, const float* __restrict__ fin_b,
                 const float* __restrict__ fout_w, const float* __restrict__ fout_b,
                 const float* __restrict__ kbuf, const float* __restrict__ vbuf,
                 const float* __restrict__ p_sscale, const float* __restrict__ p_pscale,
                 const float* __restrict__ p_skip,
                 float* __restrict__ out) {
  __shared__ __align__(16) float sA[Cc * 64];   // xn -> scores(65-stride) -> ffn xn
  __shared__ __align__(16) float sB[Cc * 64];   // g/prod -> k -> v -> hidden
  __shared__ __align__(16) float sQH[Cc * 64];  // query_h (kept for skip)
  __shared__ __align__(16) float sQ[Cc * 64];   // q -> attended -> ffn prod
  __shared__ float sr[64];
  const int tid = threadIdx.x;
  const int bid = blockIdx.x;
  const int fr = bid >> 3;
  const int tile = bid & 7;
  const int b = fr >> 7, t = fr & 127;
  const int fbase = tile * 64;
  const size_t sbase = ((size_t)b * Cc * Tt + t) * Ff + fbase;  // side[b,0,t,fbase]
  const float sscale = *p_sscale;
  const float pscale = *p_pscale;
  const float skip = *p_skip;
  const int f0 = (tid & 15) * 4;
  const int o0 = (tid >> 4) * 4;

  // 1: load side tile + rmsnorm (in place)
#pragma unroll
  for (int i = 0; i < 16; ++i) {
    int idx = i * 512 + tid;
    sA[idx] = side[sbase + (size_t)(idx >> 6) * Tt * Ff + (idx & 63)];
  }
  __syncthreads();
  if (tid < 64) {
    float s = 0.f;
    for (int c = 0; c < Cc; ++c) { float v = sA[c * 64 + tid]; s += v * v; }
    sr[tid] = rsqrtf(s * (1.0f / Cc) + 1e-6f);
  }
  __syncthreads();
#pragma unroll
  for (int i = 0; i < 16; ++i) {
    int idx = i * 512 + tid;
    sA[idx] *= sr[idx & 63] * qn_gamma[idx >> 6];
  }
  __syncthreads();

  // 2: g = silu(in_w[C+o] @ xn + b[C+o]) -> sB
  {
    float acc[4][4] = {};
    mm_core128(qin_w + 128 * 128, sA, o0, f0, acc);
#pragma unroll
    for (int j = 0; j < 4; ++j) {
      float bb = qin_b[128 + o0 + j];
#pragma unroll
      for (int i = 0; i < 4; ++i) sB[(o0 + j) * 64 + f0 + i] = silu_f(acc[j][i] + bb);
    }
  }
  // 3: prod = (in_w[o] @ xn + b[o]) * silu_g  (same-thread elements, no sync needed)
  {
    float acc[4][4] = {};
    mm_core128(qin_w, sA, o0, f0, acc);
#pragma unroll
    for (int j = 0; j < 4; ++j) {
      float bb = qin_b[o0 + j];
#pragma unroll
      for (int i = 0; i < 4; ++i) {
        int p = (o0 + j) * 64 + f0 + i;
        sB[p] = (acc[j][i] + bb) * sB[p];
      }
    }
  }
  __syncthreads();
  // 4: query_h = out_w @ prod + out_b -> sQH
  {
    float acc[4][4] = {};
    mm_core128(qout_w, sB, o0, f0, acc);
#pragma unroll
    for (int j = 0; j < 4; ++j) {
      float bb = qout_b[o0 + j];
#pragma unroll
      for (int i = 0; i < 4; ++i) sQH[(o0 + j) * 64 + f0 + i] = acc[j][i] + bb;
    }
  }
  __syncthreads();
  // 5: q = q_w @ query_h + q_b -> sQ ; load k -> sB
  {
    float acc[4][4] = {};
    mm_core128(q_w, sQH, o0, f0, acc);
#pragma unroll
    for (int j = 0; j < 4; ++j) {
      float bb = q_b[o0 + j];
#pragma unroll
      for (int i = 0; i < 4; ++i) sQ[(o0 + j) * 64 + f0 + i] = acc[j][i] + bb;
    }
  }
#pragma unroll
  for (int i = 0; i < 16; ++i) {
    int idx = i * 512 + tid;
    sB[idx] = kbuf[(size_t)fr * (Cc * Kk) + idx];
  }
  __syncthreads();
  // 6: scores[f][kk] = scale * q[:,f].k[:,kk] + basis[kk][fglob]*pscale  -> sA (stride 65)
  {
    const int kk0 = (tid & 15) * 4;
    const int fg = tid >> 4;  // 0..31, f = fg*2 + jj
    float acc[2][4] = {};
    for (int c = 0; c < 128; ++c) {
      float4 kv = *(const float4*)(sB + c * 64 + kk0);
      float2 qv = *(const float2*)(sQ + c * 64 + fg * 2);
      acc[0][0] += qv.x * kv.x; acc[0][1] += qv.x * kv.y;
      acc[0][2] += qv.x * kv.z; acc[0][3] += qv.x * kv.w;
      acc[1][0] += qv.y * kv.x; acc[1][1] += qv.y * kv.y;
      acc[1][2] += qv.y * kv.z; acc[1][3] += qv.y * kv.w;
    }
#pragma unroll
    for (int jj = 0; jj < 2; ++jj) {
      int f = fg * 2 + jj;
#pragma unroll
      for (int i = 0; i < 4; ++i) {
        int kkp = kk0 + i;
        sA[f * 65 + kkp] = acc[jj][i] * sscale + basis[(size_t)kkp * Ff + fbase + f] * pscale;
      }
    }
  }
  __syncthreads();
  // 7: softmax rows (tid<64); others load v -> sB
#pragma unroll
  for (int i = 0; i < 16; ++i) {
    int idx = i * 512 + tid;
    sB[idx] = vbuf[(size_t)fr * (Cc * Kk) + idx];
  }
  if (tid < 64) {
    float* row = sA + tid * 65;
    float m = row[0];
    for (int k2 = 1; k2 < 64; ++k2) m = fmaxf(m, row[k2]);
    float s = 0.f;
    for (int k2 = 0; k2 < 64; ++k2) { float e = __expf(row[k2] - m); row[k2] = e; s += e; }
    float inv = 1.0f / s;
    for (int k2 = 0; k2 < 64; ++k2) row[k2] *= inv;
  }
  __syncthreads();
  // 9: attended[c][f] = sum_kk v[c][kk]*w[f][kk] -> sQ (q is dead)
  {
    float acc[4][4] = {};
    for (int k2 = 0; k2 < 64; ++k2) {
      float vv0 = sB[(o0 + 0) * 64 + k2];
      float vv1 = sB[(o0 + 1) * 64 + k2];
      float vv2 = sB[(o0 + 2) * 64 + k2];
      float vv3 = sB[(o0 + 3) * 64 + k2];
      float w0 = sA[(f0 + 0) * 65 + k2];
      float w1 = sA[(f0 + 1) * 65 + k2];
      float w2 = sA[(f0 + 2) * 65 + k2];
      float w3 = sA[(f0 + 3) * 65 + k2];
      acc[0][0] += vv0 * w0; acc[0][1] += vv0 * w1; acc[0][2] += vv0 * w2; acc[0][3] += vv0 * w3;
      acc[1][0] += vv1 * w0; acc[1][1] += vv1 * w1; acc[1][2] += vv1 * w2; acc[1][3] += vv1 * w3;
      acc[2][0] += vv2 * w0; acc[2][1] += vv2 * w1; acc[2][2] += vv2 * w2; acc[2][3] += vv2 * w3;
      acc[3][0] += vv3 * w0; acc[3][1] += vv3 * w1; acc[3][2] += vv3 * w2; acc[3][3] += vv3 * w3;
    }
#pragma unroll
    for (int j = 0; j < 4; ++j)
#pragma unroll
      for (int i = 0; i < 4; ++i) sQ[(o0 + j) * 64 + f0 + i] = acc[j][i];
  }
  __syncthreads();
  // 10: hidden = o_w @ attended + o_b + skip * query_h -> sB (v is dead)
  {
    float acc[4][4] = {};
    mm_core128(o_w, sQ, o0, f0, acc);
#pragma unroll
    for (int j = 0; j < 4; ++j) {
      float bb = o_b[o0 + j];
#pragma unroll
      for (int i = 0; i < 4; ++i) {
        int p = (o0 + j) * 64 + f0 + i;
        sB[p] = acc[j][i] + bb + skip * sQH[p];
      }
    }
  }
  __syncthreads();
  // 11: ffn rmsnorm(hidden) -> sA (weights dead)
  if (tid < 64) {
    float s = 0.f;
    for (int c = 0; c < Cc; ++c) { float v = sB[c * 64 + tid]; s += v * v; }
    sr[tid] = rsqrtf(s * (1.0f / Cc) + 1e-6f);
  }
  __syncthreads();
#pragma unroll
  for (int i = 0; i < 16; ++i) {
    int idx = i * 512 + tid;
    sA[idx] = sB[idx] * sr[idx & 63] * ffn_gamma[idx >> 6];
  }
  __syncthreads();
  // 12: ffn g -> sQ (attended dead)
  {
    float acc[4][4] = {};
    mm_core128(fin_w + 128 * 128, sA, o0, f0, acc);
#pragma unroll
    for (int j = 0; j < 4; ++j) {
      float bb = fin_b[128 + o0 + j];
#pragma unroll
      for (int i = 0; i < 4; ++i) sQ[(o0 + j) * 64 + f0 + i] = silu_f(acc[j][i] + bb);
    }
  }
  // 13: ffn prod (same-thread)
  {
    float acc[4][4] = {};
    mm_core128(fin_w, sA, o0, f0, acc);
#pragma unroll
    for (int j = 0; j < 4; ++j) {
      float bb = fin_b[o0 + j];
#pragma unroll
      for (int i = 0; i < 4; ++i) {
        int p = (o0 + j) * 64 + f0 + i;
        sQ[p] = (acc[j][i] + bb) * sQ[p];
      }
    }
  }
  __syncthreads();
  // 14: out = ffn_out_w @ prod + ffn_out_b + hidden
  {
    float acc[4][4] = {};
    mm_core128(fout_w, sQ, o0, f0, acc);
    float* op = out + ((size_t)b * Cc * Tt + t) * Ff + fbase;  // + o*T*F + f
#pragma unroll
    for (int j = 0; j < 4; ++j) {
      float bb = fout_b[o0 + j];
#pragma unroll
      for (int i = 0; i < 4; ++i) {
        op[(size_t)(o0 + j) * Tt * Ff + f0 + i] = acc[j][i] + bb + sB[(o0 + j) * 64 + f0 + i];
      }
    }
  }
}

extern "C" void kernel_launch(void* const* d_in, const int* in_sizes, int n_in,
                              void* d_out, int out_size, void* d_ws, size_t ws_size,
                              hipStream_t stream) {
  const float* latent    = (const float*)d_in[0];
  const float* side      = (const float*)d_in[1];
  const float* basis     = (const float*)d_in[2];
  const float* lp_gamma  = (const float*)d_in[3];
  const float* lp_w      = (const float*)d_in[4];
  const float* lp_b      = (const float*)d_in[5];
  const float* qn_gamma  = (const float*)d_in[6];
  const float* qin_w     = (const float*)d_in[7];
  const float* qin_b     = (const float*)d_in[8];
  const float* qout_w    = (const float*)d_in[9];
  const float* qout_b    = (const float*)d_in[10];
  const float* q_w       = (const float*)d_in[11];
  const float* q_b       = (const float*)d_in[12];
  const float* k_w       = (const float*)d_in[13];
  const float* k_b       = (const float*)d_in[14];
  const float* v_w       = (const float*)d_in[15];
  const float* v_b       = (const float*)d_in[16];
  const float* o_w       = (const float*)d_in[17];
  const float* o_b       = (const float*)d_in[18];
  const float* ffn_gamma = (const float*)d_in[19];
  const float* fin_w     = (const float*)d_in[20];
  const float* fin_b     = (const float*)d_in[21];
  const float* fout_w    = (const float*)d_in[22];
  const float* fout_b    = (const float*)d_in[23];
  const float* sscale    = (const float*)d_in[24];
  const float* pscale    = (const float*)d_in[25];
  const float* skipsc    = (const float*)d_in[26];

  float* kbuf = (float*)d_ws;                       // [1024][128][64]
  float* vbuf = kbuf + (size_t)1024 * Cc * Kk;      // [1024][128][64]

  kv_kernel<<<dim3(1024), dim3(512), 0, stream>>>(
      latent, lp_gamma, lp_w, lp_b, k_w, k_b, v_w, v_b, kbuf, vbuf);
  main_kernel<<<dim3(8192), dim3(512), 0, stream>>>(
      side, basis, qn_gamma, qin_w, qin_b, qout_w, qout_b, q_w, q_b, o_w, o_b,
      ffn_gamma, fin_w, fin_b, fout_w, fout_b, kbuf, vbuf,
      sscale, pscale, skipsc, (float*)d_out);
}

// Round 2
// 1112.476 us; speedup vs baseline: 2.7857x; 2.7857x over previous
//
#include <hip/hip_runtime.h>

// B=8, C=128, T=128, F=512, K=64 — bf16 MFMA pipeline (32x32x16 + 16x16x32)
static constexpr int Cc = 128, Tt = 128, Ff = 512, Kk = 64;
static constexpr int SR = 136;  // LDS activation row stride (bf16 elems), [64 f][136 c]
static constexpr int PR = 88;   // LDS P-matrix row stride

typedef __bf16 bf16x8 __attribute__((ext_vector_type(8)));
typedef __bf16 bf16x4 __attribute__((ext_vector_type(4)));
typedef float f32x16 __attribute__((ext_vector_type(16)));
typedef float f32x4 __attribute__((ext_vector_type(4)));

__device__ __forceinline__ f32x16 z16() {
  f32x16 v;
#pragma unroll
  for (int i = 0; i < 16; ++i) v[i] = 0.f;
  return v;
}
__device__ __forceinline__ f32x4 z4() {
  f32x4 v;
#pragma unroll
  for (int i = 0; i < 4; ++i) v[i] = 0.f;
  return v;
}
__device__ __forceinline__ float silu_f(float x) { return x / (1.0f + __expf(-x)); }

// RMSNorm over c (=128) per f-row of an LDS [64][SR] bf16 tile. dst may == src.
__device__ __forceinline__ void rmsnorm_lds(const __bf16* __restrict__ src,
                                            __bf16* __restrict__ dst,
                                            const float* __restrict__ gamma,
                                            float* sPart, float* sr, int tid) {
  {
    int f = tid >> 2, s2 = tid & 3;
    const __bf16* p = src + f * SR + s2 * 32;
    float sum = 0.f;
#pragma unroll
    for (int k = 0; k < 4; ++k) {
      bf16x8 v = *(const bf16x8*)(p + k * 8);
#pragma unroll
      for (int j = 0; j < 8; ++j) { float x = (float)v[j]; sum += x * x; }
    }
    sPart[f * 4 + s2] = sum;
  }
  __syncthreads();
  if (tid < 64) {
    float s = sPart[tid * 4] + sPart[tid * 4 + 1] + sPart[tid * 4 + 2] + sPart[tid * 4 + 3];
    sr[tid] = rsqrtf(s * (1.f / 128.f) + 1e-6f);
  }
  __syncthreads();
#pragma unroll
  for (int i = 0; i < 32; ++i) {
    int idx = i * 256 + tid;
    int f = idx >> 7, c = idx & 127;
    dst[f * SR + c] = (__bf16)((float)src[f * SR + c] * sr[f] * gamma[c]);
  }
}

// Y^T[f][o] = sum_c X[f][c] * W[o][c]; X = LDS [64][SR] bf16 (A-op), W = global bf16
// row-major [>=128][128] (B-op). 4 waves: wave = (o-pair <<1) | f-tile. Each wave: two
// 32x32 D tiles (t=0,1 -> o base p*64 + t*32). epi(acc, t) handles bias/act/store.
template <typename EPI>
__device__ __forceinline__ void unit_std(const __bf16* __restrict__ X,
                                         const __bf16* __restrict__ W,
                                         int lane, int wave, EPI epi) {
  const int h = lane >> 5, ol = lane & 31;
  const int p = wave >> 1, mt = wave & 1;
  const int oA = p * 64 + ol;
  bf16x8 B0[8], B1[8];
#pragma unroll
  for (int s = 0; s < 8; ++s) {
    B0[s] = *(const bf16x8*)(W + (size_t)oA * 128 + s * 16 + h * 8);
    B1[s] = *(const bf16x8*)(W + (size_t)(oA + 32) * 128 + s * 16 + h * 8);
  }
  f32x16 a0 = z16(), a1 = z16();
  const __bf16* Ar = X + (mt * 32 + ol) * SR + h * 8;
#pragma unroll
  for (int s = 0; s < 8; ++s) {
    bf16x8 Af = *(const bf16x8*)(Ar + s * 16);
    a0 = __builtin_amdgcn_mfma_f32_32x32x16_bf16(Af, B0[s], a0, 0, 0, 0);
    a1 = __builtin_amdgcn_mfma_f32_32x32x16_bf16(Af, B1[s], a1, 0, 0, 0);
  }
  epi(a0, 0);
  epi(a1, 1);
}

// ---------------- weight conversion ----------------
struct PrepArgs {
  const float* src[9];
  int n[9];
};
__global__ __launch_bounds__(256) void prep_kernel(PrepArgs pa, __bf16* __restrict__ dst) {
  int off = 0;
  for (int m = 0; m < 9; ++m) {
    const float* s = pa.src[m];
    int n = pa.n[m];
    for (int i = blockIdx.x * 256 + threadIdx.x; i < n; i += gridDim.x * 256)
      dst[off + i] = (__bf16)s[i];
    off += n;
  }
}

// ---------------- kv kernel ----------------
__global__ __launch_bounds__(256, 2)
void kv_kernel(const float* __restrict__ latent, const float* __restrict__ lp_gamma,
               const float* __restrict__ lp_b, const float* __restrict__ k_b,
               const float* __restrict__ v_b,
               const __bf16* __restrict__ w_lp, const __bf16* __restrict__ w_k,
               const __bf16* __restrict__ w_v,
               __bf16* __restrict__ kbuf, __bf16* __restrict__ vbuf) {
  __shared__ __align__(16) __bf16 S0[64 * SR];
  __shared__ __align__(16) __bf16 S1[64 * SR];
  __shared__ float sPart[256];
  __shared__ float sr[64];
  const int tid = threadIdx.x;
  const int lane = tid & 63, wave = tid >> 6;
  const int h = lane >> 5, ol = lane & 31;
  const int fr = blockIdx.x;
  const int b = fr >> 7, t = fr & 127;
  const size_t lbase = ((size_t)b * Cc * Tt + t) * Kk;

  // load latent [c][kk] -> S0 [kk][c] bf16
#pragma unroll
  for (int i = 0; i < 32; ++i) {
    int idx = i * 256 + tid;
    int c = idx >> 6, kk = idx & 63;
    S0[kk * SR + c] = (__bf16)latent[lbase + (size_t)c * Tt * Kk + kk];
  }
  __syncthreads();
  rmsnorm_lds(S0, S0, lp_gamma, sPart, sr, tid);
  __syncthreads();

  // latent_h = silu(lp @ xn + b) -> S1
  unit_std(S0, w_lp, lane, wave, [&](const f32x16& a, int tix) {
    int o = (wave >> 1) * 64 + tix * 32 + ol;
    int mt = wave & 1;
    float bb = lp_b[o];
#pragma unroll
    for (int r = 0; r < 16; ++r) {
      int f = mt * 32 + (r & 3) + 8 * (r >> 2) + 4 * h;
      S1[f * SR + o] = (__bf16)silu_f(a[r] + bb);
    }
  });
  __syncthreads();

  // k -> kbuf [kk][c] (transposed), v -> vbuf [c][kk]
  __bf16* kb = kbuf + (size_t)fr * 8192;
  unit_std(S1, w_k, lane, wave, [&](const f32x16& a, int tix) {
    int o = (wave >> 1) * 64 + tix * 32 + ol;
    int mt = wave & 1;
    float bb = k_b[o];
#pragma unroll
    for (int r = 0; r < 16; ++r) {
      int kkr = mt * 32 + (r & 3) + 8 * (r >> 2) + 4 * h;
      kb[kkr * 128 + o] = (__bf16)(a[r] + bb);
    }
  });
  __bf16* vb = vbuf + (size_t)fr * 8192;
  unit_std(S1, w_v, lane, wave, [&](const f32x16& a, int tix) {
    int o = (wave >> 1) * 64 + tix * 32 + ol;
    int mt = wave & 1;
    float bb = v_b[o];
    __bf16* vbo = vb + (size_t)o * 64 + mt * 32;
#pragma unroll
    for (int q = 0; q < 4; ++q) {
      bf16x4 pk;
      pk[0] = (__bf16)(a[4 * q + 0] + bb);
      pk[1] = (__bf16)(a[4 * q + 1] + bb);
      pk[2] = (__bf16)(a[4 * q + 2] + bb);
      pk[3] = (__bf16)(a[4 * q + 3] + bb);
      *(bf16x4*)(vbo + 8 * q + 4 * h) = pk;
    }
  });
}

// ---------------- main kernel ----------------
__global__ __launch_bounds__(256, 2)
void main_kernel(const float* __restrict__ side, const float* __restrict__ basis,
                 const float* __restrict__ qn_gamma,
                 const float* __restrict__ qin_b, const float* __restrict__ qout_b,
                 const float* __restrict__ q_b, const float* __restrict__ o_b,
                 const float* __restrict__ ffn_gamma,
                 const float* __restrict__ fin_b, const float* __restrict__ fout_b,
                 const __bf16* __restrict__ w_qin, const __bf16* __restrict__ w_qout,
                 const __bf16* __restrict__ w_q, const __bf16* __restrict__ w_o,
                 const __bf16* __restrict__ w_fin, const __bf16* __restrict__ w_fout,
                 const __bf16* __restrict__ kbuf, const __bf16* __restrict__ vbuf,
                 const float* __restrict__ p_sscale, const float* __restrict__ p_pscale,
                 const float* __restrict__ p_skip, float* __restrict__ out) {
  __shared__ __align__(16) __bf16 S0[64 * SR];
  __shared__ __align__(16) __bf16 S1[64 * SR];
  __shared__ __align__(16) __bf16 S2[64 * SR];
  __shared__ __align__(16) __bf16 PM[64 * PR];
  __shared__ float sPart[256];
  __shared__ float sr[64];
  const int tid = threadIdx.x;
  const int lane = tid & 63, wave = tid >> 6;
  const int h = lane >> 5, ol = lane & 31;
  const int bid = blockIdx.x;
  const int fr = bid >> 3, tile = bid & 7;
  const int b = fr >> 7, t = fr & 127;
  const int fbase = tile * 64;
  const size_t sbase = ((size_t)b * Cc * Tt + t) * Ff + fbase;
  const float sscale = *p_sscale, pscale = *p_pscale, skip = *p_skip;
  const __bf16* kfr = kbuf + (size_t)fr * 8192;
  const __bf16* vfr = vbuf + (size_t)fr * 8192;

  // phase 1: load side tile -> S0 [f][c] bf16; rmsnorm in place
#pragma unroll
  for (int i = 0; i < 32; ++i) {
    int idx = i * 256 + tid;
    int c = idx >> 6, f = idx & 63;
    S0[f * SR + c] = (__bf16)side[sbase + (size_t)c * Tt * Ff + f];
  }
  __syncthreads();
  rmsnorm_lds(S0, S0, qn_gamma, sPart, sr, tid);
  __syncthreads();

  // phase 2: qmlp swiglu: gate then up*silu(gate) -> S1
  {
    float sg[2][16];
    unit_std(S0, w_qin + 128 * 128, lane, wave, [&](const f32x16& a, int tix) {
      int o = (wave >> 1) * 64 + tix * 32 + ol;
      float bb = qin_b[128 + o];
#pragma unroll
      for (int r = 0; r < 16; ++r) sg[tix][r] = silu_f(a[r] + bb);
    });
    unit_std(S0, w_qin, lane, wave, [&](const f32x16& a, int tix) {
      int o = (wave >> 1) * 64 + tix * 32 + ol;
      int mt = wave & 1;
      float bb = qin_b[o];
#pragma unroll
      for (int r = 0; r < 16; ++r) {
        int f = mt * 32 + (r & 3) + 8 * (r >> 2) + 4 * h;
        S1[f * SR + o] = (__bf16)((a[r] + bb) * sg[tix][r]);
      }
    });
  }
  __syncthreads();

  // phase 3: query_h -> S2
  unit_std(S1, w_qout, lane, wave, [&](const f32x16& a, int tix) {
    int o = (wave >> 1) * 64 + tix * 32 + ol;
    int mt = wave & 1;
    float bb = qout_b[o];
#pragma unroll
    for (int r = 0; r < 16; ++r) {
      int f = mt * 32 + (r & 3) + 8 * (r >> 2) + 4 * h;
      S2[f * SR + o] = (__bf16)(a[r] + bb);
    }
  });
  __syncthreads();

  // phase 4: q -> S0
  unit_std(S2, w_q, lane, wave, [&](const f32x16& a, int tix) {
    int o = (wave >> 1) * 64 + tix * 32 + ol;
    int mt = wave & 1;
    float bb = q_b[o];
#pragma unroll
    for (int r = 0; r < 16; ++r) {
      int f = mt * 32 + (r & 3) + 8 * (r >> 2) + 4 * h;
      S0[f * SR + o] = (__bf16)(a[r] + bb);
    }
  });
  __syncthreads();

  // phase 5: scores (16x16x32; wave = f-group of 16) + in-wave softmax -> PM
  {
    const int q4 = lane >> 4, li = lane & 15;
    const int fw = wave * 16;
    f32x4 acc[4] = {z4(), z4(), z4(), z4()};
    const __bf16* Ar = S0 + (fw + li) * SR + q4 * 8;
    const __bf16* Kr = kfr + li * 128 + q4 * 8;
#pragma unroll
    for (int s = 0; s < 4; ++s) {
      bf16x8 Af = *(const bf16x8*)(Ar + s * 32);
#pragma unroll
      for (int nt = 0; nt < 4; ++nt) {
        bf16x8 Bf = *(const bf16x8*)(Kr + nt * (16 * 128) + s * 32);
        acc[nt] = __builtin_amdgcn_mfma_f32_16x16x32_bf16(Af, Bf, acc[nt], 0, 0, 0);
      }
    }
    float sc[4][4];
#pragma unroll
    for (int nt = 0; nt < 4; ++nt)
#pragma unroll
      for (int r = 0; r < 4; ++r) {
        int kk = 16 * nt + li;
        int f = fw + 4 * q4 + r;
        sc[nt][r] = acc[nt][r] * sscale + pscale * basis[(size_t)kk * Ff + fbase + f];
      }
#pragma unroll
    for (int r = 0; r < 4; ++r) {
      float m = fmaxf(fmaxf(sc[0][r], sc[1][r]), fmaxf(sc[2][r], sc[3][r]));
      m = fmaxf(m, __shfl_xor(m, 1));
      m = fmaxf(m, __shfl_xor(m, 2));
      m = fmaxf(m, __shfl_xor(m, 4));
      m = fmaxf(m, __shfl_xor(m, 8));
      float e[4], ssum = 0.f;
#pragma unroll
      for (int nt = 0; nt < 4; ++nt) { e[nt] = __expf(sc[nt][r] - m); ssum += e[nt]; }
      ssum += __shfl_xor(ssum, 1);
      ssum += __shfl_xor(ssum, 2);
      ssum += __shfl_xor(ssum, 4);
      ssum += __shfl_xor(ssum, 8);
      float inv = 1.f / ssum;
      int f = fw + 4 * q4 + r;
#pragma unroll
      for (int nt = 0; nt < 4; ++nt) PM[f * PR + 16 * nt + li] = (__bf16)(e[nt] * inv);
    }
  }
  __syncthreads();

  // phase 6: attended^T[f][c] (wave = c-group of 32) -> S1
  {
    const __bf16* Vr = vfr + (size_t)(wave * 32 + ol) * 64 + h * 8;
    bf16x8 Bv[4];
#pragma unroll
    for (int s = 0; s < 4; ++s) Bv[s] = *(const bf16x8*)(Vr + s * 16);
    f32x16 a0 = z16(), a1 = z16();
    const __bf16* Ar = PM + ol * PR + h * 8;
#pragma unroll
    for (int s = 0; s < 4; ++s) {
      bf16x8 A0 = *(const bf16x8*)(Ar + s * 16);
      bf16x8 A1 = *(const bf16x8*)(Ar + 32 * PR + s * 16);
      a0 = __builtin_amdgcn_mfma_f32_32x32x16_bf16(A0, Bv[s], a0, 0, 0, 0);
      a1 = __builtin_amdgcn_mfma_f32_32x32x16_bf16(A1, Bv[s], a1, 0, 0, 0);
    }
    int c = wave * 32 + ol;
#pragma unroll
    for (int r = 0; r < 16; ++r) {
      int fl = (r & 3) + 8 * (r >> 2) + 4 * h;
      S1[fl * SR + c] = (__bf16)a0[r];
      S1[(32 + fl) * SR + c] = (__bf16)a1[r];
    }
  }
  __syncthreads();

  // phase 7: hidden = o@attended + b + skip*qh -> S0
  unit_std(S1, w_o, lane, wave, [&](const f32x16& a, int tix) {
    int o = (wave >> 1) * 64 + tix * 32 + ol;
    int mt = wave & 1;
    float bb = o_b[o];
#pragma unroll
    for (int r = 0; r < 16; ++r) {
      int f = mt * 32 + (r & 3) + 8 * (r >> 2) + 4 * h;
      S0[f * SR + o] = (__bf16)(a[r] + bb + skip * (float)S2[f * SR + o]);
    }
  });
  __syncthreads();

  // phase 8: ffn rmsnorm(hidden) -> S2
  rmsnorm_lds(S0, S2, ffn_gamma, sPart, sr, tid);
  __syncthreads();

  // phase 9: ffn swiglu -> S1
  {
    float sg[2][16];
    unit_std(S2, w_fin + 128 * 128, lane, wave, [&](const f32x16& a, int tix) {
      int o = (wave >> 1) * 64 + tix * 32 + ol;
      float bb = fin_b[128 + o];
#pragma unroll
      for (int r = 0; r < 16; ++r) sg[tix][r] = silu_f(a[r] + bb);
    });
    unit_std(S2, w_fin, lane, wave, [&](const f32x16& a, int tix) {
      int o = (wave >> 1) * 64 + tix * 32 + ol;
      int mt = wave & 1;
      float bb = fin_b[o];
#pragma unroll
      for (int r = 0; r < 16; ++r) {
        int f = mt * 32 + (r & 3) + 8 * (r >> 2) + 4 * h;
        S1[f * SR + o] = (__bf16)((a[r] + bb) * sg[tix][r]);
      }
    });
  }
  __syncthreads();

  // phase 10: out = fout@prod + b + hidden -> global (float4 runs of 4 consecutive f)
  unit_std(S1, w_fout, lane, wave, [&](const f32x16& a, int tix) {
    int o = (wave >> 1) * 64 + tix * 32 + ol;
    int mt = wave & 1;
    float bb = fout_b[o];
    float* op = out + (((size_t)b * 128 + o) * 128 + t) * 512 + fbase + mt * 32;
#pragma unroll
    for (int q = 0; q < 4; ++q) {
      int f0l = 8 * q + 4 * h;
      float4 v;
      v.x = a[4 * q + 0] + bb + (float)S0[(mt * 32 + f0l + 0) * SR + o];
      v.y = a[4 * q + 1] + bb + (float)S0[(mt * 32 + f0l + 1) * SR + o];
      v.z = a[4 * q + 2] + bb + (float)S0[(mt * 32 + f0l + 2) * SR + o];
      v.w = a[4 * q + 3] + bb + (float)S0[(mt * 32 + f0l + 3) * SR + o];
      *(float4*)(op + f0l) = v;
    }
  });
}

extern "C" void kernel_launch(void* const* d_in, const int* in_sizes, int n_in,
                              void* d_out, int out_size, void* d_ws, size_t ws_size,
                              hipStream_t stream) {
  const float* latent    = (const float*)d_in[0];
  const float* side      = (const float*)d_in[1];
  const float* basis     = (const float*)d_in[2];
  const float* lp_gamma  = (const float*)d_in[3];
  const float* lp_w      = (const float*)d_in[4];
  const float* lp_b      = (const float*)d_in[5];
  const float* qn_gamma  = (const float*)d_in[6];
  const float* qin_w     = (const float*)d_in[7];
  const float* qin_b     = (const float*)d_in[8];
  const float* qout_w    = (const float*)d_in[9];
  const float* qout_b    = (const float*)d_in[10];
  const float* q_w       = (const float*)d_in[11];
  const float* q_b       = (const float*)d_in[12];
  const float* k_w       = (const float*)d_in[13];
  const float* k_b       = (const float*)d_in[14];
  const float* v_w       = (const float*)d_in[15];
  const float* v_b       = (const float*)d_in[16];
  const float* o_w       = (const float*)d_in[17];
  const float* o_b       = (const float*)d_in[18];
  const float* ffn_gamma = (const float*)d_in[19];
  const float* fin_w     = (const float*)d_in[20];
  const float* fin_b     = (const float*)d_in[21];
  const float* fout_w    = (const float*)d_in[22];
  const float* fout_b    = (const float*)d_in[23];
  const float* sscale    = (const float*)d_in[24];
  const float* pscale    = (const float*)d_in[25];
  const float* skipsc    = (const float*)d_in[26];

  __bf16* wsb = (__bf16*)d_ws;
  __bf16* kbuf = wsb;                                  // 1024*64*128
  __bf16* vbuf = wsb + (size_t)1024 * 8192;            // 1024*128*64
  __bf16* wbase = wsb + (size_t)2048 * 8192;
  // order: lp, qin, qout, q, k, v, o, fin, fout
  __bf16* w_lp   = wbase;
  __bf16* w_qin  = w_lp + 16384;
  __bf16* w_qout = w_qin + 32768;
  __bf16* w_q    = w_qout + 16384;
  __bf16* w_k    = w_q + 16384;
  __bf16* w_v    = w_k + 16384;
  __bf16* w_o    = w_v + 16384;
  __bf16* w_fin  = w_o + 16384;
  __bf16* w_fout = w_fin + 32768;

  PrepArgs pa;
  pa.src[0] = lp_w;   pa.n[0] = 16384;
  pa.src[1] = qin_w;  pa.n[1] = 32768;
  pa.src[2] = qout_w; pa.n[2] = 16384;
  pa.src[3] = q_w;    pa.n[3] = 16384;
  pa.src[4] = k_w;    pa.n[4] = 16384;
  pa.src[5] = v_w;    pa.n[5] = 16384;
  pa.src[6] = o_w;    pa.n[6] = 16384;
  pa.src[7] = fin_w;  pa.n[7] = 32768;
  pa.src[8] = fout_w; pa.n[8] = 16384;

  prep_kernel<<<dim3(64), dim3(256), 0, stream>>>(pa, wbase);
  kv_kernel<<<dim3(1024), dim3(256), 0, stream>>>(
      latent, lp_gamma, lp_b, k_b, v_b, w_lp, w_k, w_v, kbuf, vbuf);
  main_kernel<<<dim3(8192), dim3(256), 0, stream>>>(
      side, basis, qn_gamma, qin_b, qout_b, q_b, o_b, ffn_gamma, fin_b, fout_b,
      w_qin, w_qout, w_q, w_o, w_fin, w_fout, kbuf, vbuf,
      sscale, pscale, skipsc, (float*)d_out);
}